// Round 12
// baseline (101211.890 us; speedup 1.0000x reference)
//
#include <hip/hip_runtime.h>
#include <math.h>

// mLSTM scan, 8192 serial steps. Weights resident on-chip (wh_w f32 in
// regs/AGPRs; wmh_w bf16-packed in LDS: 32KB/CU), one persistent
// workgroup per CU (256 x 256), per-step cross-CU exchange of the
// 2048-vectors m and h via tagged bf16x2 packets at device scope.
// FC chain on block 0.
//
// R11 -> R12: REVERT atomic reads (RMW serialization regressed 22%).
// R9 base with ONE conceptual change: ONLY WAVE 0 POLLS.
// Theory: the surviving invariant across R5..R11 is the poll sweep's own
// request throughput -- 512 sc1 loads/CU (131K chip-wide) per sweep, all
// served past L2, saturate the fabric/MALL request rate and make the
// sweep period (= detect latency) ~2-3us. Concentrating the poll in wave
// 0 (64 lanes x 8 dwordx4 = 128 loads/CU) cuts chip-wide poll requests
// 4x. Waves 1-3 park at the EXISTING __syncthreads (same 2 barriers/step).
// Wave 0 stages packed value-dwords to LDS; consumers unpack (1 VALU op;
// lanes 2k/2k+1 broadcast-share a bank -> conflict-free).
//
// LDS buffer lifetime safety (2 barriers/step, same as R9):
//  - stage_pkH(t+1) written by wave 0 after it passes SYNC_B(t); all
//    hloc(t) reads happen between SYNC_A(t) and SYNC_B(t).  OK.
//  - stage_pkM(t) written by wave 0 after SYNC_A(t); all mloc(t-1) reads
//    happen before any wave enters SYNC_A(t).  OK.

#define WS_HP   0          // h packets: 1024 x (bf16x2, tag) = 2048 words
#define WS_MP   2048       // m packets: 2048 words
#define WS_HF   4096       // final h: 2048 x (f32, tag) = 4096 words
#define WS_CF   8192       // final c: 4096 words
#define WS_TOT  12288      // words (48 KB)

typedef unsigned u32x4 __attribute__((ext_vector_type(4)));
typedef unsigned u32x2 __attribute__((ext_vector_type(2)));
typedef unsigned long long u64;

__device__ __forceinline__ float sigm(float x) { return 1.f / (1.f + __expf(-x)); }

__device__ __forceinline__ float wred(float v) {
  v += __shfl_xor(v, 32, 64);
  v += __shfl_xor(v, 16, 64);
  v += __shfl_xor(v, 8, 64);
  v += __shfl_xor(v, 4, 64);
  v += __shfl_xor(v, 2, 64);
  v += __shfl_xor(v, 1, 64);
  return v;
}

// RNE f32 -> bf16 bits (low 16).
__device__ __forceinline__ unsigned bf(float f) {
  unsigned x = __float_as_uint(f);
  return (x + 0x7fffu + ((x >> 16) & 1u)) >> 16;
}

// One 8B packet: (bf16 v0 | bf16 v1 << 16, tag32), device-scope store.
__device__ __forceinline__ void store_pack(unsigned* p, float v0, float v1,
                                           unsigned tag) {
  u32x2 q; q.x = bf(v0) | (bf(v1) << 16); q.y = tag;
  asm volatile("global_store_dwordx2 %0, %1, off sc1"
               :: "v"(p), "v"(q) : "memory");
}

// f32 (value, tag) pair store (finals only), device scope.
__device__ __forceinline__ void store_pair(unsigned* p, float v, unsigned tag) {
  u32x2 q; q.x = __float_as_uint(v); q.y = tag;
  asm volatile("global_store_dwordx2 %0, %1, off sc1"
               :: "v"(p), "v"(q) : "memory");
}

// Wave-0 poll unit: 16 packets (128B) in 8 dwordx4 loads, one vmcnt(0).
// True when all 16 tags == expect; value dwords delivered in ov[0..15].
__device__ __forceinline__ bool poll16(const unsigned* p, unsigned expect,
                                       unsigned* ov) {
  u32x4 a0, a1, a2, a3, a4, a5, a6, a7;
  asm volatile(
      "global_load_dwordx4 %0, %8, off sc1\n\t"
      "global_load_dwordx4 %1, %8, off offset:16 sc1\n\t"
      "global_load_dwordx4 %2, %8, off offset:32 sc1\n\t"
      "global_load_dwordx4 %3, %8, off offset:48 sc1\n\t"
      "global_load_dwordx4 %4, %8, off offset:64 sc1\n\t"
      "global_load_dwordx4 %5, %8, off offset:80 sc1\n\t"
      "global_load_dwordx4 %6, %8, off offset:96 sc1\n\t"
      "global_load_dwordx4 %7, %8, off offset:112 sc1\n\t"
      "s_waitcnt vmcnt(0)"
      : "=&v"(a0), "=&v"(a1), "=&v"(a2), "=&v"(a3),
        "=&v"(a4), "=&v"(a5), "=&v"(a6), "=&v"(a7)
      : "v"(p)
      : "memory");
  unsigned bad = (a0.y ^ expect) | (a0.w ^ expect)
               | (a1.y ^ expect) | (a1.w ^ expect)
               | (a2.y ^ expect) | (a2.w ^ expect)
               | (a3.y ^ expect) | (a3.w ^ expect)
               | (a4.y ^ expect) | (a4.w ^ expect)
               | (a5.y ^ expect) | (a5.w ^ expect)
               | (a6.y ^ expect) | (a6.w ^ expect)
               | (a7.y ^ expect) | (a7.w ^ expect);
  ov[0]  = a0.x; ov[1]  = a0.z; ov[2]  = a1.x; ov[3]  = a1.z;
  ov[4]  = a2.x; ov[5]  = a2.z; ov[6]  = a3.x; ov[7]  = a3.z;
  ov[8]  = a4.x; ov[9]  = a4.z; ov[10] = a5.x; ov[11] = a5.z;
  ov[12] = a6.x; ov[13] = a6.z; ov[14] = a7.x; ov[15] = a7.z;
  return bad == 0;
}

// Wave 0, lane l: poll packets 16l..16l+15 until fresh, stage the 16
// packed value-dwords to LDS stage_pk[16l..16l+15].
__device__ __forceinline__ void wave_poll_stage(const unsigned* packs_u32,
                                                unsigned expect,
                                                unsigned* stage_pk, int lane) {
  const unsigned* p = packs_u32 + 32 * lane;   // 128B chunk
  unsigned ov[16];
  while (!poll16(p, expect, ov)) __builtin_amdgcn_s_sleep(1);
  uint4* dst = (uint4*)(stage_pk + 16 * lane);
  dst[0] = make_uint4(ov[0],  ov[1],  ov[2],  ov[3]);
  dst[1] = make_uint4(ov[4],  ov[5],  ov[6],  ov[7]);
  dst[2] = make_uint4(ov[8],  ov[9],  ov[10], ov[11]);
  dst[3] = make_uint4(ov[12], ov[13], ov[14], ov[15]);
}

// Scalar f32 pair poll (FC tail only), device scope.
__device__ __forceinline__ float poll1(const unsigned* p, unsigned expect) {
  for (;;) {
    u32x2 q;
    asm volatile("global_load_dwordx2 %0, %1, off sc1\n\t"
                 "s_waitcnt vmcnt(0)"
                 : "=&v"(q) : "v"(p) : "memory");
    if (q.y == expect) return __uint_as_float(q.x);
    __builtin_amdgcn_s_sleep(1);
  }
}

__global__ __launch_bounds__(256, 1)
void mlstm_kernel(const int* __restrict__ tokens,
                  const float* __restrict__ embed_w,
                  const float* __restrict__ wx_w,  const float* __restrict__ wx_b,
                  const float* __restrict__ wh_w,  const float* __restrict__ wh_b,
                  const float* __restrict__ wmx_w, const float* __restrict__ wmx_b,
                  const float* __restrict__ wmh_w, const float* __restrict__ wmh_b,
                  const float* __restrict__ fc1_w, const float* __restrict__ fc1_b,
                  const float* __restrict__ fc2_w, const float* __restrict__ fc2_b,
                  const float* __restrict__ fc3_w, const float* __restrict__ fc3_b,
                  const float* __restrict__ fc4_w, const float* __restrict__ fc4_b,
                  float* __restrict__ out, float* __restrict__ ws)
{
  __shared__ unsigned wmh_pk[8][16][64];          // 32KB: wmh rows, bf16x2 packed
  __shared__ __align__(16) float fcx[4096];       // stage_pkH (loop) / FC scratch
  __shared__ __align__(16) float fy[2048];        // stage_pkM (loop) / FC scratch

  const int tid  = threadIdx.x;
  const int lane = tid & 63;
  const int wv   = tid >> 6;        // wave 0..3 owns units 2wv, 2wv+1
  const int b    = blockIdx.x;      // CU id 0..255

  unsigned* h_pack = (unsigned*)ws + WS_HP;
  unsigned* m_pack = (unsigned*)ws + WS_MP;
  unsigned* hF     = (unsigned*)ws + WS_HF;
  unsigned* cF     = (unsigned*)ws + WS_CF;
  unsigned* stage_pkH = (unsigned*)fcx;   // 1024 packed dwords
  unsigned* stage_pkM = (unsigned*)fy;    // 1024 packed dwords

  // ---------------- preload weights ----------------
  // s = 4*rr + type: wave wv, unit u = 8b + 2wv + rr, row = 2048*type + u.
  float whR[8][32];
  float wxR[8][2];
  float gBias[8];
#pragma unroll
  for (int s = 0; s < 8; ++s) {
    const int rs = 2048 * (s & 3) + 8 * b + 2 * wv + (s >> 2);
    const float* row = wh_w + (size_t)rs * 2048;
#pragma unroll
    for (int j = 0; j < 32; ++j) whR[s][j] = row[lane + 64 * j];
    wxR[s][0] = wx_w[(size_t)rs * 128 + lane];
    wxR[s][1] = wx_w[(size_t)rs * 128 + lane + 64];
    gBias[s] = wh_b[rs] + wx_b[rs];
  }
  float wmxR[2][2], vB[2], xB[2];
#pragma unroll
  for (int rr = 0; rr < 2; ++rr) {
    const int gu = 8 * b + 2 * wv + rr;
    wmxR[rr][0] = wmx_w[(size_t)gu * 128 + lane];
    wmxR[rr][1] = wmx_w[(size_t)gu * 128 + lane + 64];
    vB[rr] = wmh_b[gu];
    xB[rr] = wmx_b[gu];
  }
  // wmh rows -> LDS as packed bf16 pairs (RNE).
  for (int idx = tid; idx < 8 * 16 * 64; idx += 256) {
    int u = idx >> 10, p = (idx >> 6) & 15, l = idx & 63;
    float a = wmh_w[(size_t)(8 * b + u) * 2048 + l + 128 * p];
    float c = wmh_w[(size_t)(8 * b + u) * 2048 + l + 128 * p + 64];
    wmh_pk[u][p][l] = bf(a) | (bf(c) << 16);
  }
  __syncthreads();

  const int half_hi = lane & 1;    // odd lane -> high bf16 of packed dword
  float c0 = 0.f, c1 = 0.f;        // f32 c-state
  int tok = tokens[0];
  float e0 = embed_w[tok * 128 + lane];
  float e1 = embed_w[tok * 128 + lane + 64];

  for (int t = 0; t < 8192; ++t) {
    // ---- phase 1: wave 0 polls h(t) (tag t; t=0 from memset zeros) ----
    if (wv == 0)
      wave_poll_stage(h_pack, (unsigned)t, stage_pkH, lane);
    __syncthreads();                       // SYNC_A
    float hloc[32];
    {
      const unsigned* spk = stage_pkH + (lane >> 1);
#pragma unroll
      for (int j = 0; j < 32; ++j) {
        unsigned pk = spk[32 * j];
        hloc[j] = __uint_as_float(half_hi ? (pk & 0xffff0000u) : (pk << 16));
      }
    }
    float mv[2];
#pragma unroll
    for (int rr = 0; rr < 2; ++rr) {
      float acc = 0.f;
#pragma unroll
      for (int p = 0; p < 16; ++p) {
        unsigned pk = wmh_pk[2 * wv + rr][p][lane];
        acc = fmaf(__uint_as_float(pk << 16),         hloc[2 * p],     acc);
        acc = fmaf(__uint_as_float(pk & 0xffff0000u), hloc[2 * p + 1], acc);
      }
      float ax = fmaf(wmxR[rr][0], e0, wmxR[rr][1] * e1);
      acc = wred(acc);
      ax  = wred(ax);
      mv[rr] = (ax + xB[rr]) * (acc + vB[rr]);   // m = xm * (wmh@h + b)
    }
    if (lane == 0)
      store_pack(m_pack + 2 * (4 * b + wv), mv[0], mv[1], (unsigned)(t + 1));

    // ---- phase 2: wave 0 polls m(t) (tag t+1) ----
    if (wv == 0)
      wave_poll_stage(m_pack, (unsigned)(t + 1), stage_pkM, lane);
    __syncthreads();                       // SYNC_B
    float mloc[32];
    {
      const unsigned* spk = stage_pkM + (lane >> 1);
#pragma unroll
      for (int j = 0; j < 32; ++j) {
        unsigned pk = spk[32 * j];
        mloc[j] = __uint_as_float(half_hi ? (pk & 0xffff0000u) : (pk << 16));
      }
    }
    float ga[8];
#pragma unroll
    for (int s = 0; s < 8; ++s) {
      float acc = fmaf(wxR[s][0], e0, wxR[s][1] * e1);   // x_gates folded in
#pragma unroll
      for (int j = 0; j < 32; ++j) acc = fmaf(whR[s][j], mloc[j], acc);
      ga[s] = acc;
    }
    // prefetch next token + embedding (hides under reductions)
    if (t + 1 < 8192) {
      tok = tokens[t + 1];
      e0 = embed_w[tok * 128 + lane];
      e1 = embed_w[tok * 128 + lane + 64];
    }
#pragma unroll
    for (int s = 0; s < 8; ++s) ga[s] = wred(ga[s]) + gBias[s];
    // all lanes compute identically (ga uniform after wred); lane0 stores
    c0 = sigm(ga[1]) * c0 + sigm(ga[0]) * tanhf(ga[2]);
    float h0 = sigm(ga[3]) * tanhf(c0);
    c1 = sigm(ga[5]) * c1 + sigm(ga[4]) * tanhf(ga[6]);
    float h1 = sigm(ga[7]) * tanhf(c1);
    if (lane == 0) {
      if (t + 1 < 8192) {
        store_pack(h_pack + 2 * (4 * b + wv), h0, h1, (unsigned)(t + 1));
      } else {
        // finals as exact f32 pairs
        const int u = 8 * b + 2 * wv;
        store_pair(hF + 2 * u,       h0, 8193u);
        store_pair(hF + 2 * (u + 1), h1, 8193u);
        store_pair(cF + 2 * u,       c0, 8193u);
        store_pair(cF + 2 * (u + 1), c1, 8193u);
      }
    }
  }

  if (b != 0) return;

  // ---- final FC chain on block 0 only (~10 MMAC) ----
  for (int i = tid; i < 2048; i += 256) {
    fcx[i]        = poll1(hF + 2 * i, 8193u);
    fcx[2048 + i] = poll1(cF + 2 * i, 8193u);
  }
  __syncthreads();
  // fc1: [2048 x 4096]
  for (int r = tid; r < 2048; r += 256) {
    const float4* wr = (const float4*)(fc1_w + (size_t)r * 4096);
    const float4* xv = (const float4*)fcx;
    float a0 = 0, a1 = 0, a2 = 0, a3 = 0;
    for (int k = 0; k < 1024; ++k) {
      float4 w = wr[k], x = xv[k];
      a0 = fmaf(w.x, x.x, a0); a1 = fmaf(w.y, x.y, a1);
      a2 = fmaf(w.z, x.z, a2); a3 = fmaf(w.w, x.w, a3);
    }
    fy[r] = fmaxf((a0 + a1) + (a2 + a3) + fc1_b[r], 0.f);
  }
  __syncthreads();
  // fc2: [512 x 2048]
  for (int r = tid; r < 512; r += 256) {
    const float4* wr = (const float4*)(fc2_w + (size_t)r * 2048);
    const float4* xv = (const float4*)fy;
    float a0 = 0, a1 = 0, a2 = 0, a3 = 0;
    for (int k = 0; k < 512; ++k) {
      float4 w = wr[k], x = xv[k];
      a0 = fmaf(w.x, x.x, a0); a1 = fmaf(w.y, x.y, a1);
      a2 = fmaf(w.z, x.z, a2); a3 = fmaf(w.w, x.w, a3);
    }
    fcx[r] = fmaxf((a0 + a1) + (a2 + a3) + fc2_b[r], 0.f);
  }
  __syncthreads();
  // fc3: [1024 x 512]
  for (int r = tid; r < 1024; r += 256) {
    const float4* wr = (const float4*)(fc3_w + (size_t)r * 512);
    const float4* xv = (const float4*)fcx;
    float a0 = 0, a1 = 0, a2 = 0, a3 = 0;
    for (int k = 0; k < 128; ++k) {
      float4 w = wr[k], x = xv[k];
      a0 = fmaf(w.x, x.x, a0); a1 = fmaf(w.y, x.y, a1);
      a2 = fmaf(w.z, x.z, a2); a3 = fmaf(w.w, x.w, a3);
    }
    fy[r] = fmaxf((a0 + a1) + (a2 + a3) + fc3_b[r], 0.f);
  }
  __syncthreads();
  // fc4: [5 x 1024]
  if (tid < 5) {
    const float4* wr = (const float4*)(fc4_w + (size_t)tid * 1024);
    const float4* xv = (const float4*)fy;
    float a0 = 0, a1 = 0, a2 = 0, a3 = 0;
    for (int k = 0; k < 256; ++k) {
      float4 w = wr[k], x = xv[k];
      a0 = fmaf(w.x, x.x, a0); a1 = fmaf(w.y, x.y, a1);
      a2 = fmaf(w.z, x.z, a2); a3 = fmaf(w.w, x.w, a3);
    }
    out[tid] = fmaxf((a0 + a1) + (a2 + a3) + fc4_b[tid], 0.f);
  }
}

extern "C" void kernel_launch(void* const* d_in, const int* in_sizes, int n_in,
                              void* d_out, int out_size, void* d_ws, size_t ws_size,
                              hipStream_t stream)
{
  const int*   tokens = (const int*)  d_in[0];
  const float* embed_w = (const float*)d_in[1];
  const float* wx_w   = (const float*)d_in[2];
  const float* wx_b   = (const float*)d_in[3];
  const float* wh_w   = (const float*)d_in[4];
  const float* wh_b   = (const float*)d_in[5];
  const float* wmx_w  = (const float*)d_in[6];
  const float* wmx_b  = (const float*)d_in[7];
  const float* wmh_w  = (const float*)d_in[8];
  const float* wmh_b  = (const float*)d_in[9];
  const float* fc1_w  = (const float*)d_in[10];
  const float* fc1_b  = (const float*)d_in[11];
  const float* fc2_w  = (const float*)d_in[12];
  const float* fc2_b  = (const float*)d_in[13];
  const float* fc3_w  = (const float*)d_in[14];
  const float* fc3_b  = (const float*)d_in[15];
  const float* fc4_w  = (const float*)d_in[16];
  const float* fc4_b  = (const float*)d_in[17];
  float* out = (float*)d_out;
  float* ws  = (float*)d_ws;

  // zero all packets/tags every call (graph-replay safe; h tag 0 == h(0)=0)
  hipMemsetAsync(d_ws, 0, WS_TOT * sizeof(unsigned), stream);

  mlstm_kernel<<<dim3(256), dim3(256), 0, stream>>>(
      tokens, embed_w, wx_w, wx_b, wh_w, wh_b,
      wmx_w, wmx_b, wmh_w, wmh_b,
      fc1_w, fc1_b, fc2_w, fc2_b, fc3_w, fc3_b,
      fc4_w, fc4_b, out, ws);
}

// Round 13
// 48968.033 us; speedup vs baseline: 2.0669x; 2.0669x over previous
//
#include <hip/hip_runtime.h>
#include <math.h>

// mLSTM scan, 8192 serial steps. Weights resident on-chip (wh_w f32 in
// regs: 256/thread; wmh_w bf16-packed in LDS: 32KB/CU), one persistent
// workgroup per CU (256 x 256), per-step cross-CU exchange of the
// 2048-vectors m and h via tagged bf16x2 packets at device scope.
// FC chain on block 0.
//
// R12 -> R13: REVERT wave-0-only polling (36% regression -- heavier
// per-poller sweep lengthened the sampling period; detection latency is
// set by sampling period, not request pressure: R10/R12 both reduced
// pressure and regressed). R9 base with the poll loop replaced by a
// maximally tight, 2-deep PIPELINED poll:
//  - no s_sleep in hot polls;
//  - two 32B sweeps in flight per thread, s_waitcnt vmcnt(2) counted
//    waits (sampling period ~RT/2 instead of ~RT);
//  - wave-collective exit (__all; tags monotone -> re-reading fresh
//    packets is safe) = uniform branch, no exec-mask divergence;
//  - sched_barrier(0) after each counted wait (hipcc hoists reg-only
//    checks past inline-asm waitcnt otherwise);
//  - drain at poll entry makes vmcnt bookkeeping exact (also covers the
//    producer's in-order store-ack, paid symmetrically by all waves).

#define WS_HP   0          // h packets: 1024 x (bf16x2, tag) = 2048 words
#define WS_MP   2048       // m packets: 2048 words
#define WS_HF   4096       // final h: 2048 x (f32, tag) = 4096 words
#define WS_CF   8192       // final c: 4096 words
#define WS_TOT  12288      // words (48 KB)

typedef unsigned u32x4 __attribute__((ext_vector_type(4)));
typedef unsigned u32x2 __attribute__((ext_vector_type(2)));

__device__ __forceinline__ float sigm(float x) { return 1.f / (1.f + __expf(-x)); }

__device__ __forceinline__ float wred(float v) {
  v += __shfl_xor(v, 32, 64);
  v += __shfl_xor(v, 16, 64);
  v += __shfl_xor(v, 8, 64);
  v += __shfl_xor(v, 4, 64);
  v += __shfl_xor(v, 2, 64);
  v += __shfl_xor(v, 1, 64);
  return v;
}

// RNE f32 -> bf16 bits (low 16).
__device__ __forceinline__ unsigned bf(float f) {
  unsigned x = __float_as_uint(f);
  return (x + 0x7fffu + ((x >> 16) & 1u)) >> 16;
}

// One 8B packet: (bf16 v0 | bf16 v1 << 16, tag32), device-scope store.
__device__ __forceinline__ void store_pack(unsigned* p, float v0, float v1,
                                           unsigned tag) {
  u32x2 q; q.x = bf(v0) | (bf(v1) << 16); q.y = tag;
  asm volatile("global_store_dwordx2 %0, %1, off sc1"
               :: "v"(p), "v"(q) : "memory");
}

// f32 (value, tag) pair store (finals only), device scope.
__device__ __forceinline__ void store_pair(unsigned* p, float v, unsigned tag) {
  u32x2 q; q.x = __float_as_uint(v); q.y = tag;
  asm volatile("global_store_dwordx2 %0, %1, off sc1"
               :: "v"(p), "v"(q) : "memory");
}

// Issue one 32B sweep (2 x dwordx4), no wait.
__device__ __forceinline__ void issue2(const unsigned* p, u32x4* A, u32x4* B) {
  asm volatile(
      "global_load_dwordx4 %0, %2, off sc1\n\t"
      "global_load_dwordx4 %1, %2, off offset:16 sc1"
      : "=&v"(*A), "=&v"(*B) : "v"(p) : "memory");
}

// Wait until only the newest sweep (2 loads) remains outstanding.
__device__ __forceinline__ void wait_older2() {
  asm volatile("s_waitcnt vmcnt(2)" ::: "memory");
  __builtin_amdgcn_sched_barrier(0);
}

// Drain all VMEM (exact vmcnt bookkeeping at poll entry/exit).
__device__ __forceinline__ void drain_all() {
  asm volatile("s_waitcnt vmcnt(0)" ::: "memory");
  __builtin_amdgcn_sched_barrier(0);
}

// All 4 packet tags match?
__device__ __forceinline__ bool fresh4(u32x4 a, u32x4 b, unsigned e) {
  unsigned bad = (a.y ^ e) | (a.w ^ e) | (b.y ^ e) | (b.w ^ e);
  return bad == 0;
}

// Tight 2-deep pipelined poll of 4 packets (32B). Wave-collective exit:
// all 64 lanes fresh. Tags are monotone (one write per step), so lanes
// that are already fresh re-read identical data until the wave exits.
__device__ __forceinline__ void poll_pipe(const unsigned* p, unsigned expect,
                                          u32x4* va, u32x4* vb) {
  u32x4 A, B, C, D;
  drain_all();
  issue2(p, &A, &B);
  issue2(p, &C, &D);
  for (;;) {
    wait_older2();                       // slot0 (A,B) complete
    if (__all(fresh4(A, B, expect))) { drain_all(); *va = A; *vb = B; return; }
    issue2(p, &A, &B);
    wait_older2();                       // slot1 (C,D) complete
    if (__all(fresh4(C, D, expect))) { drain_all(); *va = C; *vb = D; return; }
    issue2(p, &C, &D);
  }
}

// Scalar f32 pair poll (FC tail only), device scope.
__device__ __forceinline__ float poll1(const unsigned* p, unsigned expect) {
  for (;;) {
    u32x2 q;
    asm volatile("global_load_dwordx2 %0, %1, off sc1\n\t"
                 "s_waitcnt vmcnt(0)"
                 : "=&v"(q) : "v"(p) : "memory");
    if (q.y == expect) return __uint_as_float(q.x);
    __builtin_amdgcn_s_sleep(1);
  }
}

// Unpack 8 bf16 scalars from 2 packets' value-dwords into LDS stage.
__device__ __forceinline__ void stage8(float* s, u32x4 a, u32x4 b) {
  s[0] = __uint_as_float(a.x << 16);
  s[1] = __uint_as_float(a.x & 0xffff0000u);
  s[2] = __uint_as_float(a.z << 16);
  s[3] = __uint_as_float(a.z & 0xffff0000u);
  s[4] = __uint_as_float(b.x << 16);
  s[5] = __uint_as_float(b.x & 0xffff0000u);
  s[6] = __uint_as_float(b.z << 16);
  s[7] = __uint_as_float(b.z & 0xffff0000u);
}

__global__ __launch_bounds__(256, 1)
void mlstm_kernel(const int* __restrict__ tokens,
                  const float* __restrict__ embed_w,
                  const float* __restrict__ wx_w,  const float* __restrict__ wx_b,
                  const float* __restrict__ wh_w,  const float* __restrict__ wh_b,
                  const float* __restrict__ wmx_w, const float* __restrict__ wmx_b,
                  const float* __restrict__ wmh_w, const float* __restrict__ wmh_b,
                  const float* __restrict__ fc1_w, const float* __restrict__ fc1_b,
                  const float* __restrict__ fc2_w, const float* __restrict__ fc2_b,
                  const float* __restrict__ fc3_w, const float* __restrict__ fc3_b,
                  const float* __restrict__ fc4_w, const float* __restrict__ fc4_b,
                  float* __restrict__ out, float* __restrict__ ws)
{
  __shared__ unsigned wmh_pk[8][16][64];          // 32KB: wmh rows, bf16x2 packed
  __shared__ __align__(16) float fcx[4096];       // stageH (loop) / FC scratch
  __shared__ __align__(16) float fy[2048];        // stageM (loop) / FC scratch

  const int tid  = threadIdx.x;
  const int lane = tid & 63;
  const int wv   = tid >> 6;        // wave 0..3 owns units 2wv, 2wv+1
  const int b    = blockIdx.x;      // CU id 0..255

  unsigned* h_pack = (unsigned*)ws + WS_HP;
  unsigned* m_pack = (unsigned*)ws + WS_MP;
  unsigned* hF     = (unsigned*)ws + WS_HF;
  unsigned* cF     = (unsigned*)ws + WS_CF;
  float* stageH = fcx;
  float* stageM = fy;

  // ---------------- preload weights ----------------
  // s = 4*rr + type: wave wv, unit u = 8b + 2wv + rr, row = 2048*type + u.
  float whR[8][32];
  float wxR[8][2];
  float gBias[8];
#pragma unroll
  for (int s = 0; s < 8; ++s) {
    const int rs = 2048 * (s & 3) + 8 * b + 2 * wv + (s >> 2);
    const float* row = wh_w + (size_t)rs * 2048;
#pragma unroll
    for (int j = 0; j < 32; ++j) whR[s][j] = row[lane + 64 * j];
    wxR[s][0] = wx_w[(size_t)rs * 128 + lane];
    wxR[s][1] = wx_w[(size_t)rs * 128 + lane + 64];
    gBias[s] = wh_b[rs] + wx_b[rs];
  }
  float wmxR[2][2], vB[2], xB[2];
#pragma unroll
  for (int rr = 0; rr < 2; ++rr) {
    const int gu = 8 * b + 2 * wv + rr;
    wmxR[rr][0] = wmx_w[(size_t)gu * 128 + lane];
    wmxR[rr][1] = wmx_w[(size_t)gu * 128 + lane + 64];
    vB[rr] = wmh_b[gu];
    xB[rr] = wmx_b[gu];
  }
  // wmh rows -> LDS as packed bf16 pairs (RNE).
  for (int idx = tid; idx < 8 * 16 * 64; idx += 256) {
    int u = idx >> 10, p = (idx >> 6) & 15, l = idx & 63;
    float a = wmh_w[(size_t)(8 * b + u) * 2048 + l + 128 * p];
    float c = wmh_w[(size_t)(8 * b + u) * 2048 + l + 128 * p + 64];
    wmh_pk[u][p][l] = bf(a) | (bf(c) << 16);
  }
  __syncthreads();

  float c0 = 0.f, c1 = 0.f;        // f32 c-state
  int tok = tokens[0];
  float e0 = embed_w[tok * 128 + lane];
  float e1 = embed_w[tok * 128 + lane + 64];

  for (int t = 0; t < 8192; ++t) {
    // ---- phase 1: poll h(t) (tag t; t=0 from memset zeros), stage, m ----
    {
      u32x4 va, vb;
      poll_pipe(h_pack + 8 * tid, (unsigned)t, &va, &vb);
      stage8(&stageH[8 * tid], va, vb);
    }
    __syncthreads();                       // SYNC_A
    float hloc[32];
#pragma unroll
    for (int j = 0; j < 32; ++j) hloc[j] = stageH[lane + 64 * j];
    float mv[2];
#pragma unroll
    for (int rr = 0; rr < 2; ++rr) {
      float acc = 0.f;
#pragma unroll
      for (int p = 0; p < 16; ++p) {
        unsigned pk = wmh_pk[2 * wv + rr][p][lane];
        acc = fmaf(__uint_as_float(pk << 16),         hloc[2 * p],     acc);
        acc = fmaf(__uint_as_float(pk & 0xffff0000u), hloc[2 * p + 1], acc);
      }
      float ax = fmaf(wmxR[rr][0], e0, wmxR[rr][1] * e1);
      acc = wred(acc);
      ax  = wred(ax);
      mv[rr] = (ax + xB[rr]) * (acc + vB[rr]);   // m = xm * (wmh@h + b)
    }
    if (lane == 0)
      store_pack(m_pack + 2 * (4 * b + wv), mv[0], mv[1], (unsigned)(t + 1));

    // ---- phase 2: poll m(t) (tag t+1), stage, gates, c/h update ----
    {
      u32x4 va, vb;
      poll_pipe(m_pack + 8 * tid, (unsigned)(t + 1), &va, &vb);
      stage8(&stageM[8 * tid], va, vb);
    }
    __syncthreads();                       // SYNC_B
    float mloc[32];
#pragma unroll
    for (int j = 0; j < 32; ++j) mloc[j] = stageM[lane + 64 * j];
    float ga[8];
#pragma unroll
    for (int s = 0; s < 8; ++s) {
      float acc = fmaf(wxR[s][0], e0, wxR[s][1] * e1);   // x_gates folded in
#pragma unroll
      for (int j = 0; j < 32; ++j) acc = fmaf(whR[s][j], mloc[j], acc);
      ga[s] = acc;
    }
    // prefetch next token + embedding (hides under reductions)
    if (t + 1 < 8192) {
      tok = tokens[t + 1];
      e0 = embed_w[tok * 128 + lane];
      e1 = embed_w[tok * 128 + lane + 64];
    }
#pragma unroll
    for (int s = 0; s < 8; ++s) ga[s] = wred(ga[s]) + gBias[s];
    // all lanes compute identically (ga uniform after wred); lane0 stores
    c0 = sigm(ga[1]) * c0 + sigm(ga[0]) * tanhf(ga[2]);
    float h0 = sigm(ga[3]) * tanhf(c0);
    c1 = sigm(ga[5]) * c1 + sigm(ga[4]) * tanhf(ga[6]);
    float h1 = sigm(ga[7]) * tanhf(c1);
    if (lane == 0) {
      if (t + 1 < 8192) {
        store_pack(h_pack + 2 * (4 * b + wv), h0, h1, (unsigned)(t + 1));
      } else {
        // finals as exact f32 pairs
        const int u = 8 * b + 2 * wv;
        store_pair(hF + 2 * u,       h0, 8193u);
        store_pair(hF + 2 * (u + 1), h1, 8193u);
        store_pair(cF + 2 * u,       c0, 8193u);
        store_pair(cF + 2 * (u + 1), c1, 8193u);
      }
    }
  }

  if (b != 0) return;

  // ---- final FC chain on block 0 only (~10 MMAC) ----
  for (int i = tid; i < 2048; i += 256) {
    fcx[i]        = poll1(hF + 2 * i, 8193u);
    fcx[2048 + i] = poll1(cF + 2 * i, 8193u);
  }
  __syncthreads();
  // fc1: [2048 x 4096]
  for (int r = tid; r < 2048; r += 256) {
    const float4* wr = (const float4*)(fc1_w + (size_t)r * 4096);
    const float4* xv = (const float4*)fcx;
    float a0 = 0, a1 = 0, a2 = 0, a3 = 0;
    for (int k = 0; k < 1024; ++k) {
      float4 w = wr[k], x = xv[k];
      a0 = fmaf(w.x, x.x, a0); a1 = fmaf(w.y, x.y, a1);
      a2 = fmaf(w.z, x.z, a2); a3 = fmaf(w.w, x.w, a3);
    }
    fy[r] = fmaxf((a0 + a1) + (a2 + a3) + fc1_b[r], 0.f);
  }
  __syncthreads();
  // fc2: [512 x 2048]
  for (int r = tid; r < 512; r += 256) {
    const float4* wr = (const float4*)(fc2_w + (size_t)r * 2048);
    const float4* xv = (const float4*)fy;
    float a0 = 0, a1 = 0, a2 = 0, a3 = 0;
    for (int k = 0; k < 512; ++k) {
      float4 w = wr[k], x = xv[k];
      a0 = fmaf(w.x, x.x, a0); a1 = fmaf(w.y, x.y, a1);
      a2 = fmaf(w.z, x.z, a2); a3 = fmaf(w.w, x.w, a3);
    }
    fcx[r] = fmaxf((a0 + a1) + (a2 + a3) + fc2_b[r], 0.f);
  }
  __syncthreads();
  // fc3: [1024 x 512]
  for (int r = tid; r < 1024; r += 256) {
    const float4* wr = (const float4*)(fc3_w + (size_t)r * 512);
    const float4* xv = (const float4*)fcx;
    float a0 = 0, a1 = 0, a2 = 0, a3 = 0;
    for (int k = 0; k < 128; ++k) {
      float4 w = wr[k], x = xv[k];
      a0 = fmaf(w.x, x.x, a0); a1 = fmaf(w.y, x.y, a1);
      a2 = fmaf(w.z, x.z, a2); a3 = fmaf(w.w, x.w, a3);
    }
    fy[r] = fmaxf((a0 + a1) + (a2 + a3) + fc3_b[r], 0.f);
  }
  __syncthreads();
  // fc4: [5 x 1024]
  if (tid < 5) {
    const float4* wr = (const float4*)(fc4_w + (size_t)tid * 1024);
    const float4* xv = (const float4*)fy;
    float a0 = 0, a1 = 0, a2 = 0, a3 = 0;
    for (int k = 0; k < 256; ++k) {
      float4 w = wr[k], x = xv[k];
      a0 = fmaf(w.x, x.x, a0); a1 = fmaf(w.y, x.y, a1);
      a2 = fmaf(w.z, x.z, a2); a3 = fmaf(w.w, x.w, a3);
    }
    out[tid] = fmaxf((a0 + a1) + (a2 + a3) + fc4_b[tid], 0.f);
  }
}

extern "C" void kernel_launch(void* const* d_in, const int* in_sizes, int n_in,
                              void* d_out, int out_size, void* d_ws, size_t ws_size,
                              hipStream_t stream)
{
  const int*   tokens = (const int*)  d_in[0];
  const float* embed_w = (const float*)d_in[1];
  const float* wx_w   = (const float*)d_in[2];
  const float* wx_b   = (const float*)d_in[3];
  const float* wh_w   = (const float*)d_in[4];
  const float* wh_b   = (const float*)d_in[5];
  const float* wmx_w  = (const float*)d_in[6];
  const float* wmx_b  = (const float*)d_in[7];
  const float* wmh_w  = (const float*)d_in[8];
  const float* wmh_b  = (const float*)d_in[9];
  const float* fc1_w  = (const float*)d_in[10];
  const float* fc1_b  = (const float*)d_in[11];
  const float* fc2_w  = (const float*)d_in[12];
  const float* fc2_b  = (const float*)d_in[13];
  const float* fc3_w  = (const float*)d_in[14];
  const float* fc3_b  = (const float*)d_in[15];
  const float* fc4_w  = (const float*)d_in[16];
  const float* fc4_b  = (const float*)d_in[17];
  float* out = (float*)d_out;
  float* ws  = (float*)d_ws;

  // zero all packets/tags every call (graph-replay safe; h tag 0 == h(0)=0)
  hipMemsetAsync(d_ws, 0, WS_TOT * sizeof(unsigned), stream);

  mlstm_kernel<<<dim3(256), dim3(256), 0, stream>>>(
      tokens, embed_w, wx_w, wx_b, wh_w, wh_b,
      wmx_w, wmx_b, wmh_w, wmh_b,
      fc1_w, fc1_b, fc2_w, fc2_b, fc3_w, fc3_b,
      fc4_w, fc4_b, out, ws);
}